// Round 1
// baseline (436.731 us; speedup 1.0000x reference)
//
#include <hip/hip_runtime.h>
#include <hip/hip_bf16.h>

// Problem constants
#define BATCH 256
#define DIM   2048
#define NMEM  16384   // C_CAM * P
#define PCLS  2048
#define CCAM  8
#define KSEL  50
#define T_INV 14.285714285714285714f   // 1 / 0.07
#define NBIN  4096

typedef __bf16 bf16x8 __attribute__((ext_vector_type(8)));
typedef float  f32x4  __attribute__((ext_vector_type(4)));

static __device__ __forceinline__ unsigned int f2bf(float f) {
  unsigned int u = __float_as_uint(f);
  return (u + 0x7FFFu + ((u >> 16) & 1u)) >> 16;   // RNE truncate to bf16
}
static __device__ __forceinline__ unsigned int pk2(float lo, float hi) {
  return f2bf(lo) | (f2bf(hi) << 16);
}
// logits are cosine sims in [-1,1]; map to bin 0..4095 (masked -1e30 -> bin 0)
static __device__ __forceinline__ int binof(float v) {
  float bf = fmaf(v, 1950.4762f, 2048.0f);     // 4096 / 2.1 scale
  bf = fminf(fmaxf(bf, 0.0f), 4095.0f);
  return (int)bf;
}

// ---------------------------------------------------------------------------
// Kernel 1: row-normalize inputs, cast to bf16.  grid=256 blocks x 256 thr
// ---------------------------------------------------------------------------
__global__ __launch_bounds__(256) void norm_cast_kernel(
    const float* __restrict__ in, unsigned short* __restrict__ xb) {
  __shared__ float red[256];
  const int b = blockIdx.x, t = threadIdx.x;
  const float4* row = (const float4*)(in + (size_t)b * DIM);
  float4 a0 = row[t];
  float4 a1 = row[t + 256];
  float ss = a0.x*a0.x + a0.y*a0.y + a0.z*a0.z + a0.w*a0.w
           + a1.x*a1.x + a1.y*a1.y + a1.z*a1.z + a1.w*a1.w;
  red[t] = ss; __syncthreads();
  for (int s = 128; s > 0; s >>= 1) { if (t < s) red[t] += red[t + s]; __syncthreads(); }
  const float rn = rsqrtf(red[0]);
  ushort4 o0, o1;
  o0.x = (unsigned short)f2bf(a0.x*rn); o0.y = (unsigned short)f2bf(a0.y*rn);
  o0.z = (unsigned short)f2bf(a0.z*rn); o0.w = (unsigned short)f2bf(a0.w*rn);
  o1.x = (unsigned short)f2bf(a1.x*rn); o1.y = (unsigned short)f2bf(a1.y*rn);
  o1.z = (unsigned short)f2bf(a1.z*rn); o1.w = (unsigned short)f2bf(a1.w*rn);
  *(ushort4*)&xb[(size_t)b * DIM + t * 4]         = o0;
  *(ushort4*)&xb[(size_t)b * DIM + (t + 256) * 4] = o1;
}

// ---------------------------------------------------------------------------
// Kernel 2: logits = x(bf16) @ tempV^T  (tempV fp32, converted in staging)
// BM=128, BN=32, BK=64. 256 threads = 4 waves, each wave a 32x32 sub-tile.
// grid = dim3(2, 512) = 1024 blocks -> 4 blocks/CU (16 waves, 50% occ cap).
// 2-deep register prefetch: the LDS-write of tile k waits on loads issued a
// full iteration earlier, so ~900-cycle HBM latency is covered by a whole
// MFMA phase + the other 3 resident blocks.
// Staging maps are per-INSTRUCTION coalesced: each wave load instruction
// covers fully-used contiguous row segments (A: 8 rows x 128 B; B: 4 rows
// x 256 B), vs the old per-thread-contiguous map that scattered 16 B/lane
// at 64-B stride (4x the VMEM transactions).
// ---------------------------------------------------------------------------
#define BM 128
#define BN 32
#define BK 64
#define LDT 72   // padded LDS row stride (bf16 elems): 64 + 8

__global__ __launch_bounds__(256, 4) void gemm_kernel(
    const unsigned short* __restrict__ X,   // [256][2048] bf16
    const float* __restrict__ V,            // [16384][2048] fp32
    float* __restrict__ C) {                // [256][16384] fp32
  __shared__ unsigned short As[BM * LDT];   // 18432 B
  __shared__ unsigned short Bs[BN * LDT];   //  4608 B
  const int t  = threadIdx.x;
  const int m0 = blockIdx.x * BM;
  const int n0 = blockIdx.y * BN;
  const int lane = t & 63;
  const int w    = t >> 6;
  const int wm   = w * 32;          // wave's 32-row m sub-tile

  f32x4 acc[2][2];
#pragma unroll
  for (int i = 0; i < 2; i++)
#pragma unroll
    for (int j = 0; j < 2; j++) acc[i][j] = (f32x4){0.f, 0.f, 0.f, 0.f};

  // A staging: load j covers rows (t>>3)+32j, 16 B at col (t&7)*8 elems.
  // Wave instruction footprint: rows 0..7 (x128 B contiguous) -- coalesced.
  const int ar = t >> 3;            // 0..31
  const int ac = (t & 7) * 8;       // bf16 elem col, 16 B chunks
  // B staging: load j covers rows (t>>4)+16j, 16 B at col (t&15)*4 floats.
  const int br = t >> 4;            // 0..15
  const int bc = (t & 15) * 4;      // f32 col
  const unsigned short* Xp = X + (size_t)(m0 + ar) * DIM + ac;
  const float*          Vp = V + (size_t)(n0 + br) * DIM + bc;

  // two-deep register prefetch buffers (named, statically indexed)
  uint4  A0[4], A1[4];
  float4 B0[2], B1[2];
#pragma unroll
  for (int j = 0; j < 4; j++) A0[j] = *(const uint4*)(Xp + j * 32 * DIM);
#pragma unroll
  for (int j = 0; j < 2; j++) B0[j] = *(const float4*)(Vp + j * 16 * DIM);
#pragma unroll
  for (int j = 0; j < 4; j++) A1[j] = *(const uint4*)(Xp + j * 32 * DIM + BK);
#pragma unroll
  for (int j = 0; j < 2; j++) B1[j] = *(const float4*)(Vp + j * 16 * DIM + BK);

  const int fr = lane & 15;
  const int fk = (lane >> 4) * 8;

  for (int k0 = 0; k0 < DIM; k0 += 2 * BK) {
    // ---------------- phase 0: tile k0 (from R0) ----------------
    __syncthreads();                       // prev phase's frag reads done
#pragma unroll
    for (int j = 0; j < 4; j++)
      *(uint4*)&As[(ar + 32 * j) * LDT + ac] = A0[j];
#pragma unroll
    for (int j = 0; j < 2; j++) {
      uint2 p; p.x = pk2(B0[j].x, B0[j].y); p.y = pk2(B0[j].z, B0[j].w);
      *(uint2*)&Bs[(br + 16 * j) * LDT + bc] = p;
    }
    if (k0 + 2 * BK < DIM) {               // refill R0 two tiles ahead
#pragma unroll
      for (int j = 0; j < 4; j++)
        A0[j] = *(const uint4*)(Xp + j * 32 * DIM + k0 + 2 * BK);
#pragma unroll
      for (int j = 0; j < 2; j++)
        B0[j] = *(const float4*)(Vp + j * 16 * DIM + k0 + 2 * BK);
    }
    __syncthreads();
#pragma unroll
    for (int kk = 0; kk < BK; kk += 32) {
      bf16x8 aF0 = *(const bf16x8*)&As[(wm +      fr) * LDT + kk + fk];
      bf16x8 aF1 = *(const bf16x8*)&As[(wm + 16 + fr) * LDT + kk + fk];
      bf16x8 bF0 = *(const bf16x8*)&Bs[(          fr) * LDT + kk + fk];
      bf16x8 bF1 = *(const bf16x8*)&Bs[(     16 + fr) * LDT + kk + fk];
      acc[0][0] = __builtin_amdgcn_mfma_f32_16x16x32_bf16(aF0, bF0, acc[0][0], 0, 0, 0);
      acc[0][1] = __builtin_amdgcn_mfma_f32_16x16x32_bf16(aF0, bF1, acc[0][1], 0, 0, 0);
      acc[1][0] = __builtin_amdgcn_mfma_f32_16x16x32_bf16(aF1, bF0, acc[1][0], 0, 0, 0);
      acc[1][1] = __builtin_amdgcn_mfma_f32_16x16x32_bf16(aF1, bF1, acc[1][1], 0, 0, 0);
    }

    // ---------------- phase 1: tile k0+BK (from R1) ----------------
    __syncthreads();
#pragma unroll
    for (int j = 0; j < 4; j++)
      *(uint4*)&As[(ar + 32 * j) * LDT + ac] = A1[j];
#pragma unroll
    for (int j = 0; j < 2; j++) {
      uint2 p; p.x = pk2(B1[j].x, B1[j].y); p.y = pk2(B1[j].z, B1[j].w);
      *(uint2*)&Bs[(br + 16 * j) * LDT + bc] = p;
    }
    if (k0 + 3 * BK < DIM) {               // refill R1 two tiles ahead
#pragma unroll
      for (int j = 0; j < 4; j++)
        A1[j] = *(const uint4*)(Xp + j * 32 * DIM + k0 + 3 * BK);
#pragma unroll
      for (int j = 0; j < 2; j++)
        B1[j] = *(const float4*)(Vp + j * 16 * DIM + k0 + 3 * BK);
    }
    __syncthreads();
#pragma unroll
    for (int kk = 0; kk < BK; kk += 32) {
      bf16x8 aF0 = *(const bf16x8*)&As[(wm +      fr) * LDT + kk + fk];
      bf16x8 aF1 = *(const bf16x8*)&As[(wm + 16 + fr) * LDT + kk + fk];
      bf16x8 bF0 = *(const bf16x8*)&Bs[(          fr) * LDT + kk + fk];
      bf16x8 bF1 = *(const bf16x8*)&Bs[(     16 + fr) * LDT + kk + fk];
      acc[0][0] = __builtin_amdgcn_mfma_f32_16x16x32_bf16(aF0, bF0, acc[0][0], 0, 0, 0);
      acc[0][1] = __builtin_amdgcn_mfma_f32_16x16x32_bf16(aF0, bF1, acc[0][1], 0, 0, 0);
      acc[1][0] = __builtin_amdgcn_mfma_f32_16x16x32_bf16(aF1, bF0, acc[1][0], 0, 0, 0);
      acc[1][1] = __builtin_amdgcn_mfma_f32_16x16x32_bf16(aF1, bF1, acc[1][1], 0, 0, 0);
    }
  }

  // epilogue: C/D layout col=lane&15, row=(lane>>4)*4+reg  [m89/m91 verified]
  const int cr = (lane >> 4) * 4;
  const int cc = lane & 15;
#pragma unroll
  for (int i = 0; i < 2; i++)
#pragma unroll
    for (int j = 0; j < 2; j++)
#pragma unroll
      for (int r = 0; r < 4; r++)
        C[(size_t)(m0 + wm + i * 16 + cr + r) * NMEM + (n0 + j * 16 + cc)] =
            acc[i][j][r];
}

// ---------------------------------------------------------------------------
// Kernel 3: per-row losses. One block (256 thr) per sample.
//  - intra CE over own camera bank (no max-sub: exp(v*14.3) <= 1.6e6, fp32 ok)
//  - mask 8 positives
//  - EXACT top-50 via 4096-bin LDS histogram + suffix scan; bins above the
//    boundary bin sum directly, boundary bin resolved exactly (few elems)
//  - inter logsumexp over {8 ori, 50 sel}
// ---------------------------------------------------------------------------
__global__ __launch_bounds__(256) void row_loss_kernel(
    const float* __restrict__ logits,
    const int* __restrict__ labels, const int* __restrict__ cams,
    float* __restrict__ ce_out, float* __restrict__ lossk_out) {
  __shared__ float vals[NMEM];      // 64 KB
  __shared__ int   hist[NBIN];      // 16 KB
  __shared__ float red[256];
  __shared__ int   pint[256];
  __shared__ float bl[512];         // boundary-bin value list
  __shared__ int   bcount;
  __shared__ int   bstar_s, cabove_s;

  const int b = blockIdx.x, t = threadIdx.x;
  const float4* src = (const float4*)(logits + (size_t)b * NMEM);
#pragma unroll
  for (int i = 0; i < 16; i++) ((float4*)vals)[t + 256 * i] = src[t + 256 * i];
#pragma unroll
  for (int i = 0; i < NBIN / 256; i++) hist[t + 256 * i] = 0;
  if (t == 0) bcount = 0;
  const int cam = cams[b], label = labels[b];
  __syncthreads();

  // ---- intra CE over [cam*PCLS, +PCLS) ----
  const int s0 = cam * PCLS;
  float S = 0.f;
#pragma unroll
  for (int i = 0; i < 8; i++) S += __expf(vals[s0 + t + 256 * i] * T_INV);
  red[t] = S; __syncthreads();
  for (int s = 128; s > 0; s >>= 1) { if (t < s) red[t] += red[t + s]; __syncthreads(); }
  float ov[CCAM]; float sumo = 0.f;
  if (t == 0) {
    ce_out[b] = logf(red[0]) - vals[s0 + label] * T_INV;
#pragma unroll
    for (int c = 0; c < CCAM; c++) { ov[c] = vals[c * PCLS + label]; sumo += ov[c]; }
  }
  __syncthreads();                 // t0's ov reads done before masking
  if (t < CCAM) vals[t * PCLS + label] = -1e30f;
  __syncthreads();

  // ---- histogram ----
#pragma unroll
  for (int i = 0; i < 64; i++) {
    int bin = binof(vals[t + 256 * i]);
    atomicAdd(&hist[bin], 1);
  }
  __syncthreads();

  // ---- suffix scan: find boundary bin b* with S(b*) >= K > S(b*+1) ----
  int ps = 0;
#pragma unroll
  for (int i = 0; i < 16; i++) ps += hist[t * 16 + i];
  pint[t] = ps; __syncthreads();
  if (t == 0) {
    int cum = 0, bstar = 0, cab = 0;
    for (int tc = 255; tc >= 0; tc--) {
      if (cum + pint[tc] >= KSEL) {
        for (int bi = tc * 16 + 15; bi >= tc * 16; bi--) {
          int h = hist[bi];
          if (cum + h >= KSEL) { bstar = bi; cab = cum; break; }
          cum += h;
        }
        break;
      }
      cum += pint[tc];
    }
    bstar_s = bstar; cabove_s = cab;
  }
  __syncthreads();
  const int bstar = bstar_s;

  // ---- selection pass: sum exp over bins > b*, collect boundary bin ----
  float S2 = 0.f;
#pragma unroll
  for (int i = 0; i < 64; i++) {
    float v = vals[t + 256 * i];
    int bin = binof(v);
    if (bin > bstar) S2 += __expf(v * T_INV);
    else if (bin == bstar) {
      int p = atomicAdd(&bcount, 1);
      if (p < 512) bl[p] = v;
    }
  }
  red[t] = S2; __syncthreads();
  for (int s = 128; s > 0; s >>= 1) { if (t < s) red[t] += red[t + s]; __syncthreads(); }

  if (t == 0) {
    float S2tot = red[0];
    int need = KSEL - cabove_s;
    int bc = min(bcount, 512);
    for (int r = 0; r < need; r++) {         // exact top-(need) of boundary bin
      float mx = -1e30f; int mi = 0;
      for (int i = 0; i < bc; i++) if (bl[i] > mx) { mx = bl[i]; mi = i; }
      S2tot += __expf(mx * T_INV);
      bl[mi] = -1e30f;
    }
#pragma unroll
    for (int c = 0; c < CCAM; c++) S2tot += __expf(ov[c] * T_INV);
    lossk_out[b] = logf(S2tot) - (sumo * T_INV) * (1.0f / CCAM);
  }
}

// ---------------------------------------------------------------------------
// Kernel 4: deterministic per-camera segment means -> 2 scalars.
// ---------------------------------------------------------------------------
__global__ __launch_bounds__(256) void finalize_kernel(
    const float* __restrict__ ce, const float* __restrict__ lossk,
    const int* __restrict__ cams, float* __restrict__ out) {
  __shared__ float ce_s[BATCH], lk_s[BATCH];
  __shared__ int   cam_s[BATCH];
  __shared__ float si[CCAM], sk[CCAM], cnt[CCAM];
  const int t = threadIdx.x;
  ce_s[t]  = ce[t];
  lk_s[t]  = lossk[t];
  cam_s[t] = cams[t];
  __syncthreads();
  if (t < CCAM) {
    float a = 0.f, b = 0.f; int n = 0;
    for (int i = 0; i < BATCH; i++) {
      if (cam_s[i] == t) { a += ce_s[i]; b += lk_s[i]; n++; }
    }
    si[t] = a; sk[t] = b; cnt[t] = (float)n;
  }
  __syncthreads();
  if (t == 0) {
    float li = 0.f, lk = 0.f;
    for (int c = 0; c < CCAM; c++) {
      if (cnt[c] > 0.f) { li += si[c] / cnt[c]; lk += sk[c] / cnt[c]; }
    }
    out[0] = li;
    out[1] = 0.5f * lk;
  }
}

// ---------------------------------------------------------------------------
extern "C" void kernel_launch(void* const* d_in, const int* in_sizes, int n_in,
                              void* d_out, int out_size, void* d_ws, size_t ws_size,
                              hipStream_t stream) {
  const float* inputs = (const float*)d_in[0];   // [256][2048]
  const int*   labels = (const int*)d_in[1];     // [256]
  const int*   cams   = (const int*)d_in[2];     // [256]
  const float* tempV  = (const float*)d_in[3];   // [16384][2048]
  float* out = (float*)d_out;

  char* ws = (char*)d_ws;
  unsigned short* xb  = (unsigned short*)ws;                       // 1 MB
  float* logits       = (float*)(ws + (1u << 20));                 // 16 MB
  float* ce           = (float*)(ws + (1u << 20) + (16u << 20));   // 1 KB
  float* lossk        = (float*)(ws + (1u << 20) + (16u << 20) + 1024);

  norm_cast_kernel<<<BATCH, 256, 0, stream>>>(inputs, xb);
  gemm_kernel<<<dim3(BATCH / BM, NMEM / BN), 256, 0, stream>>>(xb, tempV, logits);
  row_loss_kernel<<<BATCH, 256, 0, stream>>>(logits, labels, cams, ce, lossk);
  finalize_kernel<<<1, 256, 0, stream>>>(ce, lossk, cams, out);
}

// Round 2
// 272.340 us; speedup vs baseline: 1.6036x; 1.6036x over previous
//
#include <hip/hip_runtime.h>
#include <hip/hip_bf16.h>

// Problem constants
#define BATCH 256
#define DIM   2048
#define NMEM  16384   // C_CAM * P
#define PCLS  2048
#define CCAM  8
#define KSEL  50
#define T_INV 14.285714285714285714f   // 1 / 0.07
#define NB2   2048    // tail-histogram bins

typedef __bf16 bf16x8 __attribute__((ext_vector_type(8)));
typedef float  f32x4  __attribute__((ext_vector_type(4)));

static __device__ __forceinline__ unsigned int f2bf(float f) {
  unsigned int u = __float_as_uint(f);
  return (u + 0x7FFFu + ((u >> 16) & 1u)) >> 16;   // RNE truncate to bf16
}
static __device__ __forceinline__ unsigned int pk2(float lo, float hi) {
  return f2bf(lo) | (f2bf(hi) << 16);
}
// tail-window binning: identical codegen used in histogram + selection passes
static __device__ __forceinline__ int binw(float x, float lo, float scale) {
  int b = (int)((x - lo) * scale);
  return b > (NB2 - 1) ? (NB2 - 1) : b;
}

// ---------------------------------------------------------------------------
// Kernel 1: row-normalize inputs, cast to bf16.  grid=256 blocks x 256 thr
// ---------------------------------------------------------------------------
__global__ __launch_bounds__(256) void norm_cast_kernel(
    const float* __restrict__ in, unsigned short* __restrict__ xb) {
  __shared__ float red[256];
  const int b = blockIdx.x, t = threadIdx.x;
  const float4* row = (const float4*)(in + (size_t)b * DIM);
  float4 a0 = row[t];
  float4 a1 = row[t + 256];
  float ss = a0.x*a0.x + a0.y*a0.y + a0.z*a0.z + a0.w*a0.w
           + a1.x*a1.x + a1.y*a1.y + a1.z*a1.z + a1.w*a1.w;
  red[t] = ss; __syncthreads();
  for (int s = 128; s > 0; s >>= 1) { if (t < s) red[t] += red[t + s]; __syncthreads(); }
  const float rn = rsqrtf(red[0]);
  ushort4 o0, o1;
  o0.x = (unsigned short)f2bf(a0.x*rn); o0.y = (unsigned short)f2bf(a0.y*rn);
  o0.z = (unsigned short)f2bf(a0.z*rn); o0.w = (unsigned short)f2bf(a0.w*rn);
  o1.x = (unsigned short)f2bf(a1.x*rn); o1.y = (unsigned short)f2bf(a1.y*rn);
  o1.z = (unsigned short)f2bf(a1.z*rn); o1.w = (unsigned short)f2bf(a1.w*rn);
  *(ushort4*)&xb[(size_t)b * DIM + t * 4]         = o0;
  *(ushort4*)&xb[(size_t)b * DIM + (t + 256) * 4] = o1;
}

// ---------------------------------------------------------------------------
// Kernel 2: logits = x(bf16) @ tempV^T  (tempV fp32, converted in staging)
// BM=128, BN=32, BK=64. 256 threads = 4 waves, each wave one 32x32 sub-tile.
// grid = dim3(2, 512) = 1024 blocks -> 4 blocks/CU (vs round-0's 2).
// Single-deep prefetch in NAMED SCALARS with __launch_bounds__(256,2) —
// round-1 post-mortem: array prefetch + (256,4) VGPR cap spilled the
// buffers to scratch (WRITE_SIZE 16MB->471MB). Revert to the known-good
// register discipline; keep only the occupancy and coalescing changes.
// Staging maps are per-INSTRUCTION coalesced: each wave load covers
// contiguous full rows (A: 8 rows x 128 B; B: 8 rows x 256 B).
// ---------------------------------------------------------------------------
#define BM 128
#define BN 32
#define BK 64
#define LDT 72   // padded LDS row stride (bf16 elems): 64 + 8

__global__ __launch_bounds__(256, 2) void gemm_kernel(
    const unsigned short* __restrict__ X,   // [256][2048] bf16
    const float* __restrict__ V,            // [16384][2048] fp32
    float* __restrict__ C) {                // [256][16384] fp32
  __shared__ unsigned short As[BM * LDT];   // 18432 B
  __shared__ unsigned short Bs[BN * LDT];   //  4608 B
  const int t  = threadIdx.x;
  const int m0 = blockIdx.x * BM;
  const int n0 = blockIdx.y * BN;
  const int lane = t & 63;
  const int w    = t >> 6;
  const int wm   = w * 32;          // wave's 32-row m sub-tile

  f32x4 acc[2][2];
#pragma unroll
  for (int i = 0; i < 2; i++)
#pragma unroll
    for (int j = 0; j < 2; j++) acc[i][j] = (f32x4){0.f, 0.f, 0.f, 0.f};

  // A staging: thread (t) -> row (t>>3)+32j, 16 B at elem col (t&7)*8.
  // One wave instruction = 8 consecutive rows x 128 B contiguous each.
  const int ar = t >> 3;            // 0..31
  const int ac = (t & 7) * 8;       // bf16 elem col
  // B staging: thread -> row t>>3 (0..31), 8 consecutive floats at (t&7)*8.
  // One wave instruction = 8 consecutive rows x 256 B contiguous each.
  const int br = t >> 3;            // 0..31
  const int bc = (t & 7) * 8;       // f32 col
  const unsigned short* Xp = X + (size_t)(m0 + ar) * DIM + ac;
  const float*          Vp = V + (size_t)(n0 + br) * DIM + bc;

  // single-deep prefetch, named scalars (no arrays -> no scratch risk)
  uint4  a0 = *(const uint4*)Xp;
  uint4  a1 = *(const uint4*)(Xp + 32 * DIM);
  uint4  a2 = *(const uint4*)(Xp + 64 * DIM);
  uint4  a3 = *(const uint4*)(Xp + 96 * DIM);
  float4 b0 = *(const float4*)Vp;
  float4 b1 = *(const float4*)(Vp + 4);

  const int fr = lane & 15;
  const int fk = (lane >> 4) * 8;

  for (int k0 = 0; k0 < DIM; k0 += BK) {
    __syncthreads();   // previous iteration's frag reads done
    *(uint4*)&As[(ar     ) * LDT + ac] = a0;
    *(uint4*)&As[(ar + 32) * LDT + ac] = a1;
    *(uint4*)&As[(ar + 64) * LDT + ac] = a2;
    *(uint4*)&As[(ar + 96) * LDT + ac] = a3;
    uint4 p;
    p.x = pk2(b0.x, b0.y); p.y = pk2(b0.z, b0.w);
    p.z = pk2(b1.x, b1.y); p.w = pk2(b1.z, b1.w);
    *(uint4*)&Bs[br * LDT + bc] = p;
    __syncthreads();

    if (k0 + BK < DIM) {  // issue next-tile global loads; consumed next iter
      a0 = *(const uint4*)(Xp + k0 + BK);
      a1 = *(const uint4*)(Xp + 32 * DIM + k0 + BK);
      a2 = *(const uint4*)(Xp + 64 * DIM + k0 + BK);
      a3 = *(const uint4*)(Xp + 96 * DIM + k0 + BK);
      b0 = *(const float4*)(Vp + k0 + BK);
      b1 = *(const float4*)(Vp + k0 + BK + 4);
    }

#pragma unroll
    for (int kk = 0; kk < BK; kk += 32) {
      bf16x8 aF0 = *(const bf16x8*)&As[(wm +      fr) * LDT + kk + fk];
      bf16x8 aF1 = *(const bf16x8*)&As[(wm + 16 + fr) * LDT + kk + fk];
      bf16x8 bF0 = *(const bf16x8*)&Bs[(          fr) * LDT + kk + fk];
      bf16x8 bF1 = *(const bf16x8*)&Bs[(     16 + fr) * LDT + kk + fk];
      acc[0][0] = __builtin_amdgcn_mfma_f32_16x16x32_bf16(aF0, bF0, acc[0][0], 0, 0, 0);
      acc[0][1] = __builtin_amdgcn_mfma_f32_16x16x32_bf16(aF0, bF1, acc[0][1], 0, 0, 0);
      acc[1][0] = __builtin_amdgcn_mfma_f32_16x16x32_bf16(aF1, bF0, acc[1][0], 0, 0, 0);
      acc[1][1] = __builtin_amdgcn_mfma_f32_16x16x32_bf16(aF1, bF1, acc[1][1], 0, 0, 0);
    }
  }

  // epilogue: C/D layout col=lane&15, row=(lane>>4)*4+reg  [m89/m91 verified]
  const int cr = (lane >> 4) * 4;
  const int cc = lane & 15;
#pragma unroll
  for (int i = 0; i < 2; i++)
#pragma unroll
    for (int j = 0; j < 2; j++)
#pragma unroll
      for (int r = 0; r < 4; r++)
        C[(size_t)(m0 + wm + i * 16 + cr + r) * NMEM + (n0 + j * 16 + cc)] =
            acc[i][j][r];
}

// ---------------------------------------------------------------------------
// Kernel 3: per-row losses. One block of 1024 thr (16 waves) per sample.
// No LDS mirror of the row: logits are L2/L3-resident after the GEMM, so we
// re-read them (3 passes) from global. Positives are masked by index
// predicate ((n & 2047) == label), not by writes.
//  pass 1: masked row max + intra exp-sum over own bank (fused)
//  pass 2: tail histogram over [vmax-W, vmax], 2048 bins; widening fallback
//          loop guarantees >= K elements in window (exactness preserved)
//  pass 3: sum exp over bins > boundary; boundary bin resolved exactly
// ---------------------------------------------------------------------------
__global__ __launch_bounds__(1024) void row_loss_kernel(
    const float* __restrict__ logits,
    const int* __restrict__ labels, const int* __restrict__ cams,
    float* __restrict__ ce_out, float* __restrict__ lossk_out) {
  __shared__ float ovs[CCAM];
  __shared__ float wredA[16], wredB[16];
  __shared__ int   hist[NB2];       // 8 KB
  __shared__ int   pint[256];
  __shared__ float bl[512];         // boundary-bin value list
  __shared__ int   bcount;
  __shared__ int   bstar_s, cabove_s, totwin_s;
  __shared__ float vmax_s;

  const int b = blockIdx.x, t = threadIdx.x;
  const int lane = t & 63, wid = t >> 6;
  const int cam = cams[b], label = labels[b];
  const float* row = logits + (size_t)b * NMEM;

  if (t < CCAM) ovs[t] = row[t * PCLS + label];

  // ---- pass 1: masked max + intra exp-sum (own bank, unmasked) ----
  float vmax = -1e30f, Si = 0.f;
#pragma unroll
  for (int i = 0; i < 4; i++) {
    const int base = (t + 1024 * i) * 4;
    const float4 v = *(const float4*)(row + base);
    const float xs[4] = {v.x, v.y, v.z, v.w};
#pragma unroll
    for (int e = 0; e < 4; e++) {
      const int n = base + e;
      const float x = xs[e];
      if ((n >> 11) == cam) Si += __expf(x * T_INV);
      if ((n & (PCLS - 1)) != label) vmax = fmaxf(vmax, x);
    }
  }
#pragma unroll
  for (int off = 32; off > 0; off >>= 1) {
    vmax = fmaxf(vmax, __shfl_down(vmax, off));
    Si  += __shfl_down(Si, off);
  }
  if (lane == 0) { wredA[wid] = vmax; wredB[wid] = Si; }
  __syncthreads();
  if (t == 0) {
    float m = -1e30f, s = 0.f;
    for (int i = 0; i < 16; i++) { m = fmaxf(m, wredA[i]); s += wredB[i]; }
    vmax_s = m;
    ce_out[b] = logf(s) - ovs[cam] * T_INV;
    bcount = 0;
  }
  __syncthreads();

  // ---- pass 2: tail histogram with widening fallback ----
  float W = 0.0625f;                 // sims ~ N(0, 1/2048): top-50 span ~0.03
  float lo = 0.f, scale = 0.f;
  for (int att = 0; att < 6; ++att) {
    __syncthreads();
    for (int i = t; i < NB2; i += 1024) hist[i] = 0;
    __syncthreads();
    lo = vmax_s - W; scale = (float)NB2 / W;
#pragma unroll
    for (int i = 0; i < 4; i++) {
      const int base = (t + 1024 * i) * 4;
      const float4 v = *(const float4*)(row + base);
      const float xs[4] = {v.x, v.y, v.z, v.w};
#pragma unroll
      for (int e = 0; e < 4; e++) {
        const int n = base + e;
        const float x = xs[e];
        if (((n & (PCLS - 1)) != label) && x >= lo)
          atomicAdd(&hist[binw(x, lo, scale)], 1);
      }
    }
    __syncthreads();
    if (t < 256) {
      int ps = 0;
#pragma unroll
      for (int i = 0; i < 8; i++) ps += hist[t * 8 + i];
      pint[t] = ps;
    }
    __syncthreads();
    if (t == 0) {
      int tot = 0;
      for (int i = 0; i < 256; i++) tot += pint[i];
      totwin_s = tot;
      if (tot >= KSEL) {
        int cum = 0, bstar = 0, cab = 0;
        for (int tc = 255; tc >= 0; tc--) {
          if (cum + pint[tc] >= KSEL) {
            for (int bi = tc * 8 + 7; bi >= tc * 8; bi--) {
              int h = hist[bi];
              if (cum + h >= KSEL) { bstar = bi; cab = cum; break; }
              cum += h;
            }
            break;
          }
          cum += pint[tc];
        }
        bstar_s = bstar; cabove_s = cab;
      }
    }
    __syncthreads();
    if (totwin_s >= KSEL) break;
    W *= 8.f;
  }
  const int bstar = bstar_s;

  // ---- pass 3: selection: sum exp over bins > b*, collect boundary bin ----
  float S2 = 0.f;
#pragma unroll
  for (int i = 0; i < 4; i++) {
    const int base = (t + 1024 * i) * 4;
    const float4 v = *(const float4*)(row + base);
    const float xs[4] = {v.x, v.y, v.z, v.w};
#pragma unroll
    for (int e = 0; e < 4; e++) {
      const int n = base + e;
      const float x = xs[e];
      if (((n & (PCLS - 1)) != label) && x >= lo) {
        const int bin = binw(x, lo, scale);
        if (bin > bstar) S2 += __expf(x * T_INV);
        else if (bin == bstar) {
          int p = atomicAdd(&bcount, 1);
          if (p < 512) bl[p] = x;
        }
      }
    }
  }
#pragma unroll
  for (int off = 32; off > 0; off >>= 1) S2 += __shfl_down(S2, off);
  if (lane == 0) wredB[wid] = S2;
  __syncthreads();

  if (t == 0) {
    float S2tot = 0.f;
    for (int i = 0; i < 16; i++) S2tot += wredB[i];
    const int need = KSEL - cabove_s;
    const int bc = min(bcount, 512);
    for (int r = 0; r < need; r++) {         // exact top-(need) of boundary bin
      float mx = -1e30f; int mi = 0;
      for (int i = 0; i < bc; i++) if (bl[i] > mx) { mx = bl[i]; mi = i; }
      S2tot += __expf(mx * T_INV);
      bl[mi] = -1e30f;
    }
    float sumo = 0.f;
#pragma unroll
    for (int c = 0; c < CCAM; c++) { S2tot += __expf(ovs[c] * T_INV); sumo += ovs[c]; }
    lossk_out[b] = logf(S2tot) - (sumo * T_INV) * (1.0f / CCAM);
  }
}

// ---------------------------------------------------------------------------
// Kernel 4: deterministic per-camera segment means -> 2 scalars.
// ---------------------------------------------------------------------------
__global__ __launch_bounds__(256) void finalize_kernel(
    const float* __restrict__ ce, const float* __restrict__ lossk,
    const int* __restrict__ cams, float* __restrict__ out) {
  __shared__ float ce_s[BATCH], lk_s[BATCH];
  __shared__ int   cam_s[BATCH];
  __shared__ float si[CCAM], sk[CCAM], cnt[CCAM];
  const int t = threadIdx.x;
  ce_s[t]  = ce[t];
  lk_s[t]  = lossk[t];
  cam_s[t] = cams[t];
  __syncthreads();
  if (t < CCAM) {
    float a = 0.f, b = 0.f; int n = 0;
    for (int i = 0; i < BATCH; i++) {
      if (cam_s[i] == t) { a += ce_s[i]; b += lk_s[i]; n++; }
    }
    si[t] = a; sk[t] = b; cnt[t] = (float)n;
  }
  __syncthreads();
  if (t == 0) {
    float li = 0.f, lk = 0.f;
    for (int c = 0; c < CCAM; c++) {
      if (cnt[c] > 0.f) { li += si[c] / cnt[c]; lk += sk[c] / cnt[c]; }
    }
    out[0] = li;
    out[1] = 0.5f * lk;
  }
}

// ---------------------------------------------------------------------------
extern "C" void kernel_launch(void* const* d_in, const int* in_sizes, int n_in,
                              void* d_out, int out_size, void* d_ws, size_t ws_size,
                              hipStream_t stream) {
  const float* inputs = (const float*)d_in[0];   // [256][2048]
  const int*   labels = (const int*)d_in[1];     // [256]
  const int*   cams   = (const int*)d_in[2];     // [256]
  const float* tempV  = (const float*)d_in[3];   // [16384][2048]
  float* out = (float*)d_out;

  char* ws = (char*)d_ws;
  unsigned short* xb  = (unsigned short*)ws;                       // 1 MB
  float* logits       = (float*)(ws + (1u << 20));                 // 16 MB
  float* ce           = (float*)(ws + (1u << 20) + (16u << 20));   // 1 KB
  float* lossk        = (float*)(ws + (1u << 20) + (16u << 20) + 1024);

  norm_cast_kernel<<<BATCH, 256, 0, stream>>>(inputs, xb);
  gemm_kernel<<<dim3(BATCH / BM, NMEM / BN), 256, 0, stream>>>(xb, tempV, logits);
  row_loss_kernel<<<BATCH, 1024, 0, stream>>>(logits, labels, cams, ce, lossk);
  finalize_kernel<<<1, 256, 0, stream>>>(ce, lossk, cams, out);
}